// Round 3
// baseline (636.109 us; speedup 1.0000x reference)
//
#include <hip/hip_runtime.h>
#include <hip/hip_bf16.h>
#include <math.h>

#define SEQ   2048
#define HID   4096
#define NHEAD 32
#define HD    128
#define QKVN  12288

typedef __bf16 bf16;
typedef __bf16 bf16x8 __attribute__((ext_vector_type(8)));
typedef __bf16 bf16x4 __attribute__((ext_vector_type(4)));
typedef float  f32x4  __attribute__((ext_vector_type(4)));

#define AS1 __attribute__((address_space(1)))
#define AS3 __attribute__((address_space(3)))

__device__ __forceinline__ void gload16(const void* g, void* l) {
    __builtin_amdgcn_global_load_lds((const AS1 void*)g, (AS3 void*)l, 16, 0, 0);
}

__device__ __forceinline__ unsigned short bbits(bf16 b) {
    union { bf16 b; unsigned short u; } x; x.b = b; return x.u;
}

// ---------------- bf16 MFMA GEMM: C[M,N] = A[M,K] @ Bt[N,K]^T ----------------
// 128x128 tile, BK=32, 4 waves, 2-phase double-buffered LDS (counted overlap),
// coalesced LDS-staged epilogue. OB==0: C f32; OB==1: C bf16. 1-D grid + XCD swizzle.
template<int OB>
__global__ __launch_bounds__(256) void gemm_bt(const bf16* __restrict__ A,
                                               const bf16* __restrict__ Bt,
                                               void* __restrict__ Cv,
                                               int M, int N, int K, int gx) {
    __shared__ __attribute__((aligned(16))) char As[2][8192];
    __shared__ __attribute__((aligned(16))) char Bs[2][8192];
    __shared__ float epi[4][16][68];   // per-wave epilogue staging (68 stride: 16B-aligned rows)

    const int tid  = threadIdx.x;
    const int l    = tid & 63;
    const int wave = tid >> 6;
    const int wr   = wave >> 1, wc = wave & 1;

    // XCD-aware swizzle of the 1-D block index (nwg % 8 == 0 for both calls)
    const int nwg  = gridDim.x;
    const int orig = blockIdx.x;
    const int swz  = (orig & 7) * (nwg >> 3) + (orig >> 3);
    const int bx   = swz % gx, by = swz / gx;
    const int brow = by * 128, bcol = bx * 128;

    f32x4 acc[4][4];
    #pragma unroll
    for (int i = 0; i < 4; ++i)
        #pragma unroll
        for (int j = 0; j < 4; ++j) acc[i][j] = (f32x4){0.f, 0.f, 0.f, 0.f};

    // staging addresses (hoisted; advance 64B per K-step)
    const size_t rowb = (size_t)K * 2;
    const char* gA[2]; const char* gB[2]; int ldsOff[2];
    #pragma unroll
    for (int i = 0; i < 2; ++i) {
        int c  = i * 256 + tid;
        int r  = c >> 2, sl = c & 3;
        int so = (sl * 16) ^ ((r & 3) << 4);
        gA[i] = (const char*)A + (size_t)(brow + r) * rowb + so;
        gB[i] = (const char*)Bt + (size_t)(bcol + r) * rowb + so;
        ldsOff[i] = (i * 256 + (tid & 192)) * 16;
    }

    // fragment read offsets (fixed; buffer base alternates)
    int afo[4], bfo[4];
    #pragma unroll
    for (int f = 0; f < 4; ++f) {
        int ra = wr * 64 + f * 16 + (l & 15);
        int rb = wc * 64 + f * 16 + (l & 15);
        int sw = (((l >> 4) * 16) ^ ((l & 3) << 4));
        afo[f] = ra * 64 + sw;
        bfo[f] = rb * 64 + sw;
    }

#define STAGE(buf) do { \
        gload16(gA[0], As[buf] + ldsOff[0]); \
        gload16(gA[1], As[buf] + ldsOff[1]); \
        gload16(gB[0], Bs[buf] + ldsOff[0]); \
        gload16(gB[1], Bs[buf] + ldsOff[1]); \
        gA[0] += 64; gA[1] += 64; gB[0] += 64; gB[1] += 64; \
    } while (0)

#define COMPUTE(buf) do { \
        bf16x8 af[4], bfr[4]; \
        _Pragma("unroll") \
        for (int f = 0; f < 4; ++f) { \
            af[f]  = *(const bf16x8*)(As[buf] + afo[f]); \
            bfr[f] = *(const bf16x8*)(Bs[buf] + bfo[f]); \
        } \
        _Pragma("unroll") \
        for (int mf = 0; mf < 4; ++mf) \
            _Pragma("unroll") \
            for (int nf = 0; nf < 4; ++nf) \
                acc[mf][nf] = __builtin_amdgcn_mfma_f32_16x16x32_bf16(af[mf], bfr[nf], acc[mf][nf], 0, 0, 0); \
    } while (0)

    const int NT = K >> 5;
    STAGE(0);
    asm volatile("s_waitcnt vmcnt(0)" ::: "memory");
    __builtin_amdgcn_s_barrier();
    for (int t = 0; t < NT - 1; ++t) {
        const int cur = t & 1;
        STAGE(cur ^ 1);                 // issue next-tile loads first (hide under MFMA)
        COMPUTE(cur);
        // drain own ds_reads (regs hold data) + own staging loads, then barrier:
        // after it, everyone may overwrite buf `cur`.
        asm volatile("s_waitcnt vmcnt(0) lgkmcnt(0)" ::: "memory");
        __builtin_amdgcn_s_barrier();
    }
    COMPUTE((NT - 1) & 1);
#undef STAGE
#undef COMPUTE

    // ---------- coalesced epilogue via per-wave LDS tile ----------
    float* ep = &epi[wave][0][0];
    #pragma unroll
    for (int mf = 0; mf < 4; ++mf) {
        #pragma unroll
        for (int nf = 0; nf < 4; ++nf)
            #pragma unroll
            for (int j = 0; j < 4; ++j)
                ep[((l >> 4) * 4 + j) * 68 + nf * 16 + (l & 15)] = acc[mf][nf][j];
        if (OB == 0) {
            #pragma unroll
            for (int p = 0; p < 4; ++p) {
                int row = p * 4 + (l >> 4);
                f32x4 v = *(const f32x4*)(ep + row * 68 + (l & 15) * 4);
                size_t grow = (size_t)(brow + wr * 64 + mf * 16 + row);
                *(f32x4*)((float*)Cv + grow * N + bcol + wc * 64 + (l & 15) * 4) = v;
            }
        } else {
            #pragma unroll
            for (int p = 0; p < 2; ++p) {
                int row = p * 8 + (l >> 3);
                const float* src = ep + row * 68 + (l & 7) * 8;
                bf16x8 o;
                #pragma unroll
                for (int i = 0; i < 8; ++i) o[i] = (bf16)src[i];
                size_t grow = (size_t)(brow + wr * 64 + mf * 16 + row);
                *(bf16x8*)((bf16*)Cv + grow * N + bcol + wc * 64 + (l & 7) * 8) = o;
            }
        }
    }
}

// ---------------- f32 -> bf16 flat cast (8/thread) ----------------
__global__ __launch_bounds__(256) void cast_flat(const float* __restrict__ in,
                                                 bf16* __restrict__ out, int n8) {
    int i = blockIdx.x * 256 + threadIdx.x;
    if (i >= n8) return;
    float4 a = ((const float4*)in)[2 * i];
    float4 b = ((const float4*)in)[2 * i + 1];
    bf16x8 o = {(bf16)a.x, (bf16)a.y, (bf16)a.z, (bf16)a.w,
                (bf16)b.x, (bf16)b.y, (bf16)b.z, (bf16)b.w};
    *(bf16x8*)(out + (size_t)i * 8) = o;
}

// ---------------- f32 [R][C] -> bf16 [C][R] transpose-cast (vectorized) ----------------
__global__ __launch_bounds__(256) void cast_transpose(const float* __restrict__ in,
                                                      bf16* __restrict__ out, int R, int C) {
    __shared__ float t[64][65];
    const int r0 = blockIdx.y * 64, c0 = blockIdx.x * 64;
    #pragma unroll
    for (int i = 0; i < 4; ++i) {
        int idx = i * 256 + threadIdx.x;
        int rr = idx >> 4, c4 = (idx & 15) * 4;
        float4 v = *(const float4*)&in[(size_t)(r0 + rr) * C + c0 + c4];
        t[rr][c4] = v.x; t[rr][c4 + 1] = v.y; t[rr][c4 + 2] = v.z; t[rr][c4 + 3] = v.w;
    }
    __syncthreads();
    #pragma unroll
    for (int i = 0; i < 2; ++i) {
        int idx = i * 256 + threadIdx.x;
        int rr = idx >> 3, c8 = (idx & 7) * 8;   // out row c0+rr, cols r0+c8..+7
        bf16x8 o;
        #pragma unroll
        for (int j = 0; j < 8; ++j) o[j] = (bf16)t[c8 + j][rr];
        *(bf16x8*)&out[(size_t)(c0 + rr) * R + r0 + c8] = o;
    }
}

// ---------------- RoPE trig table: tab[s*64+d] = {cos, sin}(pos[s] * invfreq[d]) ----------------
__global__ __launch_bounds__(256) void rope_table(const int* __restrict__ pos_ids,
                                                  float2* __restrict__ tab) {
    int id = blockIdx.x * 256 + threadIdx.x;   // SEQ*64
    int s = id >> 6, d = id & 63;
    float pos = (float)pos_ids[s];
    float inv = expf(-9.210340371976184f * ((float)d * (1.0f / 64.0f)));
    float sn, cs;
    sincosf(pos * inv, &sn, &cs);
    tab[id] = make_float2(cs, sn);
}

// ---------------- RoPE (NeoX) + repack q,k -> [head][seq][hd] (4 dims/thread) ----------------
__global__ __launch_bounds__(256) void rope_repack(const bf16* __restrict__ qkv,
                                                   const float2* __restrict__ tab,
                                                   bf16* __restrict__ Qb,
                                                   bf16* __restrict__ Kb) {
    int id = blockIdx.x * 256 + threadIdx.x;   // SEQ*NHEAD*16
    const int d4 = (id & 15) * 4;
    const int h  = (id >> 4) & (NHEAD - 1);
    const int s  = id >> 9;

    float2 tr[4];
    #pragma unroll
    for (int i = 0; i < 4; ++i) tr[i] = tab[s * 64 + d4 + i];

    const bf16* row = qkv + (size_t)s * QKVN;
    {   // q
        bf16x4 lo = *(const bf16x4*)(row + h * HD + d4);
        bf16x4 hi = *(const bf16x4*)(row + h * HD + 64 + d4);
        bf16x4 olo, ohi;
        #pragma unroll
        for (int i = 0; i < 4; ++i) {
            float x1 = (float)lo[i], x2 = (float)hi[i];
            olo[i] = (bf16)(x1 * tr[i].x - x2 * tr[i].y);
            ohi[i] = (bf16)(x2 * tr[i].x + x1 * tr[i].y);
        }
        bf16* qo = Qb + ((size_t)h * SEQ + s) * HD;
        *(bf16x4*)(qo + d4) = olo;
        *(bf16x4*)(qo + 64 + d4) = ohi;
    }
    {   // k
        bf16x4 lo = *(const bf16x4*)(row + HID + h * HD + d4);
        bf16x4 hi = *(const bf16x4*)(row + HID + h * HD + 64 + d4);
        bf16x4 olo, ohi;
        #pragma unroll
        for (int i = 0; i < 4; ++i) {
            float x1 = (float)lo[i], x2 = (float)hi[i];
            olo[i] = (bf16)(x1 * tr[i].x - x2 * tr[i].y);
            ohi[i] = (bf16)(x2 * tr[i].x + x1 * tr[i].y);
        }
        bf16* ko = Kb + ((size_t)h * SEQ + s) * HD;
        *(bf16x4*)(ko + d4) = olo;
        *(bf16x4*)(ko + 64 + d4) = ohi;
    }
}

// ---------------- V transpose: qkv v-slice -> Vt [head][hd][seq] (vectorized) ----------------
__global__ __launch_bounds__(256) void v_transpose(const bf16* __restrict__ qkv,
                                                   bf16* __restrict__ Vt) {
    __shared__ bf16 t[64][130];
    const int h = blockIdx.y, s0 = blockIdx.x * 64;
    #pragma unroll
    for (int i = 0; i < 4; ++i) {
        int idx = i * 256 + threadIdx.x;
        int ss = idx >> 4, c8 = (idx & 15) * 8;
        bf16x8 v = *(const bf16x8*)&qkv[(size_t)(s0 + ss) * QKVN + 2 * HID + h * HD + c8];
        #pragma unroll
        for (int j = 0; j < 8; ++j) t[ss][c8 + j] = v[j];
    }
    __syncthreads();
    #pragma unroll
    for (int i = 0; i < 4; ++i) {
        int idx = i * 256 + threadIdx.x;
        int dd = idx >> 3, s8 = (idx & 7) * 8;
        bf16x8 o;
        #pragma unroll
        for (int j = 0; j < 8; ++j) o[j] = t[s8 + j][dd];
        *(bf16x8*)&Vt[((size_t)h * HD + dd) * SEQ + s0 + s8] = o;
    }
}

// ---------------- bf16 MFMA causal flash attention (unchanged from round 2) ----------------
__global__ __launch_bounds__(256) void attn_mfma(const bf16* __restrict__ Qb,
                                                 const bf16* __restrict__ Kb,
                                                 const bf16* __restrict__ Vt,
                                                 bf16* __restrict__ attn) {
    __shared__ __attribute__((aligned(16))) char Ks[64 * 256];
    __shared__ __attribute__((aligned(16))) char Vs[128 * 128];
    __shared__ __attribute__((aligned(16))) char Ps[4 * 16 * 128];
    const int tid  = threadIdx.x, l = tid & 63, wave = tid >> 6;
    const int head = blockIdx.y;
    const int qb   = gridDim.x - 1 - blockIdx.x;
    const int q0   = qb * 64;
    const int qw   = q0 + wave * 16;
    const float scale = 0.08838834764831845f;

    bf16x8 qf[4];
    const bf16* Qg = Qb + ((size_t)head * SEQ + qw + (l & 15)) * HD;
    #pragma unroll
    for (int kc = 0; kc < 4; ++kc) qf[kc] = *(const bf16x8*)(Qg + kc * 32 + (l >> 4) * 8);

    f32x4 o[8];
    #pragma unroll
    for (int i = 0; i < 8; ++i) o[i] = (f32x4){0.f, 0.f, 0.f, 0.f};
    float mrun = -1e30f, lrun = 0.f;
    const int qrow  = qw + (l & 15);
    const int ntile = qb + 1;

    const char* Kg = (const char*)(Kb + (size_t)head * SEQ * HD);
    const char* Vg = (const char*)(Vt + (size_t)head * HD * SEQ);
    char* Pw = Ps + wave * 2048;

    for (int t = 0; t < ntile; ++t) {
        const int kv0 = t * 64;
        __syncthreads();
        #pragma unroll
        for (int i = 0; i < 4; ++i) {
            int c = i * 256 + tid;
            {
                int r = c >> 4, sl = c & 15;
                int so = (sl * 16) ^ ((r & 15) << 4);
                gload16(Kg + (size_t)(kv0 + r) * 256 + so,
                        Ks + (size_t)(i * 256 + (tid & 192)) * 16);
            }
            {
                int r = c >> 3, sl = c & 7;
                int so = (sl * 16) ^ ((r & 7) << 4);
                gload16(Vg + (size_t)r * (SEQ * 2) + (size_t)kv0 * 2 + so,
                        Vs + (size_t)(i * 256 + (tid & 192)) * 16);
            }
        }
        __syncthreads();

        f32x4 st[4];
        #pragma unroll
        for (int mf = 0; mf < 4; ++mf) {
            f32x4 s = (f32x4){0.f, 0.f, 0.f, 0.f};
            #pragma unroll
            for (int kc = 0; kc < 4; ++kc) {
                int rk = mf * 16 + (l & 15);
                bf16x8 a = *(const bf16x8*)(Ks + rk * 256 +
                              ((kc * 64 + (l >> 4) * 16) ^ ((rk & 15) << 4)));
                s = __builtin_amdgcn_mfma_f32_16x16x32_bf16(a, qf[kc], s, 0, 0, 0);
            }
            st[mf] = s;
        }

        float pm = -1e30f;
        #pragma unroll
        for (int mf = 0; mf < 4; ++mf)
            #pragma unroll
            for (int j = 0; j < 4; ++j) {
                int kv = kv0 + mf * 16 + (l >> 4) * 4 + j;
                float v = (kv <= qrow) ? st[mf][j] * scale : -1e30f;
                st[mf][j] = v;
                pm = fmaxf(pm, v);
            }
        pm = fmaxf(pm, __shfl_xor(pm, 16));
        pm = fmaxf(pm, __shfl_xor(pm, 32));
        float mn   = fmaxf(mrun, pm);
        float corr = __expf(mrun - mn);
        float ls = 0.f;
        #pragma unroll
        for (int mf = 0; mf < 4; ++mf)
            #pragma unroll
            for (int j = 0; j < 4; ++j) {
                float p = __expf(st[mf][j] - mn);
                st[mf][j] = p;
                ls += p;
            }
        ls += __shfl_xor(ls, 16);
        ls += __shfl_xor(ls, 32);
        lrun = lrun * corr + ls;
        mrun = mn;

        f32x4 cv;
        #pragma unroll
        for (int r = 0; r < 4; ++r) cv[r] = __shfl(corr, (l >> 4) * 4 + r, 64);
        #pragma unroll
        for (int nf = 0; nf < 8; ++nf) o[nf] *= cv;

        #pragma unroll
        for (int mf = 0; mf < 4; ++mf)
            #pragma unroll
            for (int r = 0; r < 4; r += 2) {
                int kv = mf * 16 + (l >> 4) * 4 + r;
                unsigned pk = (unsigned)bbits((bf16)st[mf][r]) |
                              ((unsigned)bbits((bf16)st[mf][r + 1]) << 16);
                *(unsigned*)(Pw + (l & 15) * 128 + ((kv * 2) ^ ((l & 15 & 7) << 4))) = pk;
            }

        #pragma unroll
        for (int kc = 0; kc < 2; ++kc) {
            bf16x8 pa = *(const bf16x8*)(Pw + (l & 15) * 128 +
                           ((kc * 64 + (l >> 4) * 16) ^ ((l & 7) << 4)));
            #pragma unroll
            for (int nf = 0; nf < 8; ++nf) {
                int dr = nf * 16 + (l & 15);
                bf16x8 vb = *(const bf16x8*)(Vs + dr * 128 +
                               ((kc * 64 + (l >> 4) * 16) ^ ((dr & 7) << 4)));
                o[nf] = __builtin_amdgcn_mfma_f32_16x16x32_bf16(pa, vb, o[nf], 0, 0, 0);
            }
        }
    }

    float il = 1.0f / lrun;
    f32x4 iv;
    #pragma unroll
    for (int r = 0; r < 4; ++r) iv[r] = __shfl(il, (l >> 4) * 4 + r, 64);
    #pragma unroll
    for (int nf = 0; nf < 8; ++nf)
        #pragma unroll
        for (int r = 0; r < 4; ++r) {
            int row = qw + (l >> 4) * 4 + r;
            attn[(size_t)row * HID + head * HD + nf * 16 + (l & 15)] = (bf16)(o[nf][r] * iv[r]);
        }
}

extern "C" void kernel_launch(void* const* d_in, const int* in_sizes, int n_in,
                              void* d_out, int out_size, void* d_ws, size_t ws_size,
                              hipStream_t stream) {
    const float* hidden  = (const float*)d_in[0];
    const int*   pos_ids = (const int*)d_in[1];
    const float* W_qkv   = (const float*)d_in[2];
    const float* W_o     = (const float*)d_in[3];
    float*       out     = (float*)d_out;
    char*        ws      = (char*)d_ws;

    // phase-1 layout
    bf16*   Wqkv_t   = (bf16*)(ws);                 // [12288][4096] bf16 = 100663296 B
    bf16*   qkv_b    = (bf16*)(ws + 100663296);     // [2048][12288] bf16 =  50331648 B
    bf16*   hidden_b = (bf16*)(ws + 150994944);     // [2048][4096]  bf16 =  16777216 B
    float2* tab      = (float2*)(ws + 150994944);   // reuses hidden_b slot AFTER gemm1 (1 MB)
    // phase-2 layout (aliases Wqkv_t region, dead after GEMM1)
    bf16* Qb     = (bf16*)(ws);                     // [32][2048][128] 16 MB
    bf16* Kb     = (bf16*)(ws + 16777216);          // 16 MB
    bf16* Vtb    = (bf16*)(ws + 33554432);          // [32][128][2048] 16 MB
    bf16* attn_b = (bf16*)(ws + 50331648);          // [2048][4096] 16 MB
    bf16* Wo_t   = (bf16*)(ws + 67108864);          // [4096][4096] 32 MB (ends at 96 MB)

    // 1) casts
    cast_flat<<<SEQ * HID / 8 / 256, 256, 0, stream>>>(hidden, hidden_b, SEQ * HID / 8);
    cast_transpose<<<dim3(QKVN / 64, HID / 64), 256, 0, stream>>>(W_qkv, Wqkv_t, HID, QKVN);
    // 2) qkv = hidden @ W_qkv (bf16 out)
    gemm_bt<1><<<(QKVN / 128) * (SEQ / 128), 256, 0, stream>>>(hidden_b, Wqkv_t, qkv_b,
                                                               SEQ, QKVN, HID, QKVN / 128);
    // 3) RoPE table (into dead hidden_b slot) + repack; V transpose
    rope_table<<<SEQ * 64 / 256, 256, 0, stream>>>(pos_ids, tab);
    rope_repack<<<SEQ * NHEAD * 16 / 256, 256, 0, stream>>>(qkv_b, tab, Qb, Kb);
    v_transpose<<<dim3(SEQ / 64, NHEAD), 256, 0, stream>>>(qkv_b, Vtb);
    // 4) W_o transpose-cast
    cast_transpose<<<dim3(HID / 64, HID / 64), 256, 0, stream>>>(W_o, Wo_t, HID, HID);
    // 5) attention
    attn_mfma<<<dim3(SEQ / 64, NHEAD), 256, 0, stream>>>(Qb, Kb, Vtb, attn_b);
    // 6) out = attn @ W_o (f32 out)
    gemm_bt<0><<<(HID / 128) * (SEQ / 128), 256, 0, stream>>>(attn_b, Wo_t, out,
                                                              SEQ, HID, HID, HID / 128);
}

// Round 4
// 523.746 us; speedup vs baseline: 1.2145x; 1.2145x over previous
//
#include <hip/hip_runtime.h>
#include <hip/hip_bf16.h>
#include <math.h>

#define SEQ   2048
#define HID   4096
#define NHEAD 32
#define HD    128
#define QKVN  12288

typedef __bf16 bf16;
typedef __bf16 bf16x8 __attribute__((ext_vector_type(8)));
typedef __bf16 bf16x4 __attribute__((ext_vector_type(4)));
typedef float  f32x4  __attribute__((ext_vector_type(4)));

#define AS1 __attribute__((address_space(1)))
#define AS3 __attribute__((address_space(3)))

__device__ __forceinline__ void gload16(const void* g, void* l) {
    __builtin_amdgcn_global_load_lds((const AS1 void*)g, (AS3 void*)l, 16, 0, 0);
}

__device__ __forceinline__ unsigned short bbits(bf16 b) {
    union { bf16 b; unsigned short u; } x; x.b = b; return x.u;
}

// ---------------- bf16 MFMA GEMM: C[M,N] = A[M,K] @ Bt[N,K]^T ----------------
// 128x128 tile, BK=32, 4 waves, 2-phase double-buffered LDS; epilogue staged in
// the (dead) As/Bs LDS region -> 32KB total -> 5 blocks/CU. Plain 2-D grid:
// bx fastest => same-bx blocks co-XCD (Bt-panel L2 reuse; gx % 8 == 0).
template<int OB>
__global__ __launch_bounds__(256) void gemm_bt(const bf16* __restrict__ A,
                                               const bf16* __restrict__ Bt,
                                               void* __restrict__ Cv,
                                               int M, int N, int K) {
    __shared__ __attribute__((aligned(16))) char smem[32768];
    // As buf b = smem + b*8192 ; Bs buf b = smem + 16384 + b*8192
    const int tid  = threadIdx.x;
    const int l    = tid & 63;
    const int wave = tid >> 6;
    const int wr   = wave >> 1, wc = wave & 1;
    const int brow = blockIdx.y * 128, bcol = blockIdx.x * 128;

    f32x4 acc[4][4];
    #pragma unroll
    for (int i = 0; i < 4; ++i)
        #pragma unroll
        for (int j = 0; j < 4; ++j) acc[i][j] = (f32x4){0.f, 0.f, 0.f, 0.f};

    const size_t rowb = (size_t)K * 2;
    const char* gA[2]; const char* gB[2]; int ldsOff[2];
    #pragma unroll
    for (int i = 0; i < 2; ++i) {
        int c  = i * 256 + tid;
        int r  = c >> 2, sl = c & 3;
        int so = (sl * 16) ^ ((r & 3) << 4);
        gA[i] = (const char*)A + (size_t)(brow + r) * rowb + so;
        gB[i] = (const char*)Bt + (size_t)(bcol + r) * rowb + so;
        ldsOff[i] = (i * 256 + (tid & 192)) * 16;
    }

    int afo[4], bfo[4];
    #pragma unroll
    for (int f = 0; f < 4; ++f) {
        int ra = wr * 64 + f * 16 + (l & 15);
        int rb = wc * 64 + f * 16 + (l & 15);
        int sw = (((l >> 4) * 16) ^ ((l & 3) << 4));
        afo[f] = ra * 64 + sw;
        bfo[f] = rb * 64 + sw;
    }

#define STAGE(buf) do { \
        gload16(gA[0], smem + (buf) * 8192 + ldsOff[0]); \
        gload16(gA[1], smem + (buf) * 8192 + ldsOff[1]); \
        gload16(gB[0], smem + 16384 + (buf) * 8192 + ldsOff[0]); \
        gload16(gB[1], smem + 16384 + (buf) * 8192 + ldsOff[1]); \
        gA[0] += 64; gA[1] += 64; gB[0] += 64; gB[1] += 64; \
    } while (0)

#define COMPUTE(buf) do { \
        const char* Ab_ = smem + (buf) * 8192; \
        const char* Bb_ = smem + 16384 + (buf) * 8192; \
        bf16x8 af[4], bfr[4]; \
        _Pragma("unroll") \
        for (int f = 0; f < 4; ++f) { \
            af[f]  = *(const bf16x8*)(Ab_ + afo[f]); \
            bfr[f] = *(const bf16x8*)(Bb_ + bfo[f]); \
        } \
        _Pragma("unroll") \
        for (int mf = 0; mf < 4; ++mf) \
            _Pragma("unroll") \
            for (int nf = 0; nf < 4; ++nf) \
                acc[mf][nf] = __builtin_amdgcn_mfma_f32_16x16x32_bf16(af[mf], bfr[nf], acc[mf][nf], 0, 0, 0); \
    } while (0)

    const int NT = K >> 5;
    STAGE(0);
    asm volatile("s_waitcnt vmcnt(0)" ::: "memory");
    __builtin_amdgcn_s_barrier();
    for (int t = 0; t < NT - 1; ++t) {
        const int cur = t & 1;
        STAGE(cur ^ 1);                 // issue next-tile loads first (hide under MFMA)
        COMPUTE(cur);
        asm volatile("s_waitcnt vmcnt(0) lgkmcnt(0)" ::: "memory");
        __builtin_amdgcn_s_barrier();
    }
    COMPUTE((NT - 1) & 1);
#undef STAGE
#undef COMPUTE

    // ---------- coalesced epilogue staged in the dead As/Bs LDS ----------
    __syncthreads();   // all waves done reading smem as tiles
    float* ep = (float*)smem + wave * (16 * 68);
    #pragma unroll
    for (int mf = 0; mf < 4; ++mf) {
        #pragma unroll
        for (int nf = 0; nf < 4; ++nf)
            #pragma unroll
            for (int j = 0; j < 4; ++j)
                ep[((l >> 4) * 4 + j) * 68 + nf * 16 + (l & 15)] = acc[mf][nf][j];
        if (OB == 0) {
            #pragma unroll
            for (int p = 0; p < 4; ++p) {
                int row = p * 4 + (l >> 4);
                f32x4 v = *(const f32x4*)(ep + row * 68 + (l & 15) * 4);
                size_t grow = (size_t)(brow + wr * 64 + mf * 16 + row);
                *(f32x4*)((float*)Cv + grow * N + bcol + wc * 64 + (l & 15) * 4) = v;
            }
        } else {
            #pragma unroll
            for (int p = 0; p < 2; ++p) {
                int row = p * 8 + (l >> 3);
                const float* src = ep + row * 68 + (l & 7) * 8;
                bf16x8 o;
                #pragma unroll
                for (int i = 0; i < 8; ++i) o[i] = (bf16)src[i];
                size_t grow = (size_t)(brow + wr * 64 + mf * 16 + row);
                *(bf16x8*)((bf16*)Cv + grow * N + bcol + wc * 64 + (l & 7) * 8) = o;
            }
        }
    }
}

// ---------------- f32 -> bf16 flat cast (8/thread) ----------------
__global__ __launch_bounds__(256) void cast_flat(const float* __restrict__ in,
                                                 bf16* __restrict__ out, int n8) {
    int i = blockIdx.x * 256 + threadIdx.x;
    if (i >= n8) return;
    float4 a = ((const float4*)in)[2 * i];
    float4 b = ((const float4*)in)[2 * i + 1];
    bf16x8 o = {(bf16)a.x, (bf16)a.y, (bf16)a.z, (bf16)a.w,
                (bf16)b.x, (bf16)b.y, (bf16)b.z, (bf16)b.w};
    *(bf16x8*)(out + (size_t)i * 8) = o;
}

// ---------------- f32 [R][C] -> bf16 [C][R] transpose-cast (vectorized) ----------------
__global__ __launch_bounds__(256) void cast_transpose(const float* __restrict__ in,
                                                      bf16* __restrict__ out, int R, int C) {
    __shared__ float t[64][65];
    const int r0 = blockIdx.y * 64, c0 = blockIdx.x * 64;
    #pragma unroll
    for (int i = 0; i < 4; ++i) {
        int idx = i * 256 + threadIdx.x;
        int rr = idx >> 4, c4 = (idx & 15) * 4;
        float4 v = *(const float4*)&in[(size_t)(r0 + rr) * C + c0 + c4];
        t[rr][c4] = v.x; t[rr][c4 + 1] = v.y; t[rr][c4 + 2] = v.z; t[rr][c4 + 3] = v.w;
    }
    __syncthreads();
    #pragma unroll
    for (int i = 0; i < 2; ++i) {
        int idx = i * 256 + threadIdx.x;
        int rr = idx >> 3, c8 = (idx & 7) * 8;
        bf16x8 o;
        #pragma unroll
        for (int j = 0; j < 8; ++j) o[j] = (bf16)t[c8 + j][rr];
        *(bf16x8*)&out[(size_t)(c0 + rr) * R + r0 + c8] = o;
    }
}

// ---------------- RoPE trig table ----------------
__global__ __launch_bounds__(256) void rope_table(const int* __restrict__ pos_ids,
                                                  float2* __restrict__ tab) {
    int id = blockIdx.x * 256 + threadIdx.x;   // SEQ*64
    int s = id >> 6, d = id & 63;
    float pos = (float)pos_ids[s];
    float inv = expf(-9.210340371976184f * ((float)d * (1.0f / 64.0f)));
    float sn, cs;
    sincosf(pos * inv, &sn, &cs);
    tab[id] = make_float2(cs, sn);
}

// ---------------- RoPE (NeoX) + repack q,k -> [head][seq][hd] ----------------
__global__ __launch_bounds__(256) void rope_repack(const bf16* __restrict__ qkv,
                                                   const float2* __restrict__ tab,
                                                   bf16* __restrict__ Qb,
                                                   bf16* __restrict__ Kb) {
    int id = blockIdx.x * 256 + threadIdx.x;   // SEQ*NHEAD*16
    const int d4 = (id & 15) * 4;
    const int h  = (id >> 4) & (NHEAD - 1);
    const int s  = id >> 9;

    float2 tr[4];
    #pragma unroll
    for (int i = 0; i < 4; ++i) tr[i] = tab[s * 64 + d4 + i];

    const bf16* row = qkv + (size_t)s * QKVN;
    {
        bf16x4 lo = *(const bf16x4*)(row + h * HD + d4);
        bf16x4 hi = *(const bf16x4*)(row + h * HD + 64 + d4);
        bf16x4 olo, ohi;
        #pragma unroll
        for (int i = 0; i < 4; ++i) {
            float x1 = (float)lo[i], x2 = (float)hi[i];
            olo[i] = (bf16)(x1 * tr[i].x - x2 * tr[i].y);
            ohi[i] = (bf16)(x2 * tr[i].x + x1 * tr[i].y);
        }
        bf16* qo = Qb + ((size_t)h * SEQ + s) * HD;
        *(bf16x4*)(qo + d4) = olo;
        *(bf16x4*)(qo + 64 + d4) = ohi;
    }
    {
        bf16x4 lo = *(const bf16x4*)(row + HID + h * HD + d4);
        bf16x4 hi = *(const bf16x4*)(row + HID + h * HD + 64 + d4);
        bf16x4 olo, ohi;
        #pragma unroll
        for (int i = 0; i < 4; ++i) {
            float x1 = (float)lo[i], x2 = (float)hi[i];
            olo[i] = (bf16)(x1 * tr[i].x - x2 * tr[i].y);
            ohi[i] = (bf16)(x2 * tr[i].x + x1 * tr[i].y);
        }
        bf16* ko = Kb + ((size_t)h * SEQ + s) * HD;
        *(bf16x4*)(ko + d4) = olo;
        *(bf16x4*)(ko + 64 + d4) = ohi;
    }
}

// ---------------- V transpose: qkv v-slice -> Vt [head][hd][seq] ----------------
__global__ __launch_bounds__(256) void v_transpose(const bf16* __restrict__ qkv,
                                                   bf16* __restrict__ Vt) {
    __shared__ bf16 t[64][130];
    const int h = blockIdx.y, s0 = blockIdx.x * 64;
    #pragma unroll
    for (int i = 0; i < 4; ++i) {
        int idx = i * 256 + threadIdx.x;
        int ss = idx >> 4, c8 = (idx & 15) * 8;
        bf16x8 v = *(const bf16x8*)&qkv[(size_t)(s0 + ss) * QKVN + 2 * HID + h * HD + c8];
        #pragma unroll
        for (int j = 0; j < 8; ++j) t[ss][c8 + j] = v[j];
    }
    __syncthreads();
    #pragma unroll
    for (int i = 0; i < 4; ++i) {
        int idx = i * 256 + threadIdx.x;
        int dd = idx >> 3, s8 = (idx & 7) * 8;
        bf16x8 o;
        #pragma unroll
        for (int j = 0; j < 8; ++j) o[j] = t[s8 + j][dd];
        *(bf16x8*)&Vt[((size_t)h * HD + dd) * SEQ + s0 + s8] = o;
    }
}

// ---------------- bf16 MFMA causal flash attention, 2-phase K/V dbuf ----------------
// grid(x=head, y=qb): same-head blocks co-XCD (id%8 = head%8) => K/V L2-resident.
__global__ __launch_bounds__(256) void attn_mfma(const bf16* __restrict__ Qb,
                                                 const bf16* __restrict__ Kb,
                                                 const bf16* __restrict__ Vt,
                                                 bf16* __restrict__ attn) {
    __shared__ __attribute__((aligned(16))) char Ka[2][16384];   // [kv 64][256B swz]
    __shared__ __attribute__((aligned(16))) char Va[2][16384];   // [d 128][128B swz]
    __shared__ __attribute__((aligned(16))) char Ps[4 * 2048];   // per-wave [16 q][64 kv]
    const int tid  = threadIdx.x, l = tid & 63, wave = tid >> 6;
    const int head = blockIdx.x;
    const int qb   = gridDim.y - 1 - blockIdx.y;   // heavy blocks first
    const int q0   = qb * 64;
    const int qw   = q0 + wave * 16;
    const float scale = 0.08838834764831845f;

    bf16x8 qf[4];
    const bf16* Qg = Qb + ((size_t)head * SEQ + qw + (l & 15)) * HD;
    #pragma unroll
    for (int kc = 0; kc < 4; ++kc) qf[kc] = *(const bf16x8*)(Qg + kc * 32 + (l >> 4) * 8);

    f32x4 o[8];
    #pragma unroll
    for (int i = 0; i < 8; ++i) o[i] = (f32x4){0.f, 0.f, 0.f, 0.f};
    float mrun = -1e30f, lrun = 0.f;
    const int qrow  = qw + (l & 15);
    const int ntile = qb + 1;

    const char* Kg = (const char*)(Kb + (size_t)head * SEQ * HD);
    const char* Vg = (const char*)(Vt + (size_t)head * HD * SEQ);
    char* Pw = Ps + wave * 2048;

#define ASTAGE(b, t0) do { \
        const int kv0_ = (t0) * 64; \
        _Pragma("unroll") \
        for (int i = 0; i < 4; ++i) { \
            int c = i * 256 + tid; \
            int rk_ = c >> 4, slk_ = c & 15; \
            gload16(Kg + (size_t)(kv0_ + rk_) * 256 + ((slk_ * 16) ^ ((rk_ & 15) << 4)), \
                    Ka[b] + (size_t)(i * 256 + (tid & 192)) * 16); \
            int rv_ = c >> 3, slv_ = c & 7; \
            gload16(Vg + (size_t)rv_ * (SEQ * 2) + (size_t)kv0_ * 2 + ((slv_ * 16) ^ ((rv_ & 7) << 4)), \
                    Va[b] + (size_t)(i * 256 + (tid & 192)) * 16); \
        } \
    } while (0)

    ASTAGE(0, 0);
    asm volatile("s_waitcnt vmcnt(0)" ::: "memory");
    __builtin_amdgcn_s_barrier();

    for (int t = 0; t < ntile; ++t) {
        const int cur = t & 1;
        const int kv0 = t * 64;
        if (t + 1 < ntile) ASTAGE(cur ^ 1, t + 1);

        // S^T[kv][q] = K @ Q^T
        f32x4 st[4];
        __builtin_amdgcn_s_setprio(1);
        #pragma unroll
        for (int mf = 0; mf < 4; ++mf) {
            f32x4 s = (f32x4){0.f, 0.f, 0.f, 0.f};
            #pragma unroll
            for (int kc = 0; kc < 4; ++kc) {
                int rk = mf * 16 + (l & 15);
                bf16x8 a = *(const bf16x8*)(Ka[cur] + rk * 256 +
                              ((kc * 64 + (l >> 4) * 16) ^ ((rk & 15) << 4)));
                s = __builtin_amdgcn_mfma_f32_16x16x32_bf16(a, qf[kc], s, 0, 0, 0);
            }
            st[mf] = s;
        }
        __builtin_amdgcn_s_setprio(0);

        // online softmax (lane owns row qrow)
        float pm = -1e30f;
        #pragma unroll
        for (int mf = 0; mf < 4; ++mf)
            #pragma unroll
            for (int j = 0; j < 4; ++j) {
                int kv = kv0 + mf * 16 + (l >> 4) * 4 + j;
                float v = (kv <= qrow) ? st[mf][j] * scale : -1e30f;
                st[mf][j] = v;
                pm = fmaxf(pm, v);
            }
        pm = fmaxf(pm, __shfl_xor(pm, 16));
        pm = fmaxf(pm, __shfl_xor(pm, 32));
        float mn   = fmaxf(mrun, pm);
        float corr = __expf(mrun - mn);
        float ls = 0.f;
        #pragma unroll
        for (int mf = 0; mf < 4; ++mf)
            #pragma unroll
            for (int j = 0; j < 4; ++j) {
                float p = __expf(st[mf][j] - mn);
                st[mf][j] = p;
                ls += p;
            }
        ls += __shfl_xor(ls, 16);
        ls += __shfl_xor(ls, 32);
        lrun = lrun * corr + ls;
        mrun = mn;

        f32x4 cv;
        #pragma unroll
        for (int r = 0; r < 4; ++r) cv[r] = __shfl(corr, (l >> 4) * 4 + r, 64);
        #pragma unroll
        for (int nf = 0; nf < 8; ++nf) o[nf] *= cv;

        // P -> bf16 -> per-wave swizzled LDS
        #pragma unroll
        for (int mf = 0; mf < 4; ++mf)
            #pragma unroll
            for (int r = 0; r < 4; r += 2) {
                int kv = mf * 16 + (l >> 4) * 4 + r;
                unsigned pk = (unsigned)bbits((bf16)st[mf][r]) |
                              ((unsigned)bbits((bf16)st[mf][r + 1]) << 16);
                *(unsigned*)(Pw + (l & 15) * 128 + ((kv * 2) ^ ((l & 15 & 7) << 4))) = pk;
            }

        // PV
        __builtin_amdgcn_s_setprio(1);
        #pragma unroll
        for (int kc = 0; kc < 2; ++kc) {
            bf16x8 pa = *(const bf16x8*)(Pw + (l & 15) * 128 +
                           ((kc * 64 + (l >> 4) * 16) ^ ((l & 7) << 4)));
            #pragma unroll
            for (int nf = 0; nf < 8; ++nf) {
                int dr = nf * 16 + (l & 15);
                bf16x8 vb = *(const bf16x8*)(Va[cur] + dr * 128 +
                               ((kc * 64 + (l >> 4) * 16) ^ ((dr & 7) << 4)));
                o[nf] = __builtin_amdgcn_mfma_f32_16x16x32_bf16(pa, vb, o[nf], 0, 0, 0);
            }
        }
        __builtin_amdgcn_s_setprio(0);

        asm volatile("s_waitcnt vmcnt(0) lgkmcnt(0)" ::: "memory");
        __builtin_amdgcn_s_barrier();
    }
#undef ASTAGE

    float il = 1.0f / lrun;
    f32x4 iv;
    #pragma unroll
    for (int r = 0; r < 4; ++r) iv[r] = __shfl(il, (l >> 4) * 4 + r, 64);
    #pragma unroll
    for (int nf = 0; nf < 8; ++nf)
        #pragma unroll
        for (int r = 0; r < 4; ++r) {
            int row = qw + (l >> 4) * 4 + r;
            attn[(size_t)row * HID + head * HD + nf * 16 + (l & 15)] = (bf16)(o[nf][r] * iv[r]);
        }
}

extern "C" void kernel_launch(void* const* d_in, const int* in_sizes, int n_in,
                              void* d_out, int out_size, void* d_ws, size_t ws_size,
                              hipStream_t stream) {
    const float* hidden  = (const float*)d_in[0];
    const int*   pos_ids = (const int*)d_in[1];
    const float* W_qkv   = (const float*)d_in[2];
    const float* W_o     = (const float*)d_in[3];
    float*       out     = (float*)d_out;
    char*        ws      = (char*)d_ws;

    // phase-1 layout
    bf16*   Wqkv_t   = (bf16*)(ws);                 // [12288][4096] bf16 = 100663296 B
    bf16*   qkv_b    = (bf16*)(ws + 100663296);     // [2048][12288] bf16 =  50331648 B
    bf16*   hidden_b = (bf16*)(ws + 150994944);     // [2048][4096]  bf16 =  16777216 B
    float2* tab      = (float2*)(ws + 150994944);   // reuses hidden_b slot AFTER gemm1
    // phase-2 layout (aliases Wqkv_t region, dead after GEMM1)
    bf16* Qb     = (bf16*)(ws);                     // [32][2048][128] 16 MB
    bf16* Kb     = (bf16*)(ws + 16777216);          // 16 MB
    bf16* Vtb    = (bf16*)(ws + 33554432);          // [32][128][2048] 16 MB
    bf16* attn_b = (bf16*)(ws + 50331648);          // [2048][4096] 16 MB
    bf16* Wo_t   = (bf16*)(ws + 67108864);          // [4096][4096] 32 MB

    cast_flat<<<SEQ * HID / 8 / 256, 256, 0, stream>>>(hidden, hidden_b, SEQ * HID / 8);
    cast_transpose<<<dim3(QKVN / 64, HID / 64), 256, 0, stream>>>(W_qkv, Wqkv_t, HID, QKVN);
    gemm_bt<1><<<dim3(QKVN / 128, SEQ / 128), 256, 0, stream>>>(hidden_b, Wqkv_t, qkv_b,
                                                                SEQ, QKVN, HID);
    rope_table<<<SEQ * 64 / 256, 256, 0, stream>>>(pos_ids, tab);
    rope_repack<<<SEQ * NHEAD * 16 / 256, 256, 0, stream>>>(qkv_b, tab, Qb, Kb);
    v_transpose<<<dim3(SEQ / 64, NHEAD), 256, 0, stream>>>(qkv_b, Vtb);
    cast_transpose<<<dim3(HID / 64, HID / 64), 256, 0, stream>>>(W_o, Wo_t, HID, HID);
    attn_mfma<<<dim3(NHEAD, SEQ / 64), 256, 0, stream>>>(Qb, Kb, Vtb, attn_b);
    gemm_bt<0><<<dim3(HID / 128, SEQ / 128), 256, 0, stream>>>(attn_b, Wo_t, out,
                                                               SEQ, HID, HID);
}